// Round 3
// baseline (191.045 us; speedup 1.0000x reference)
//
#include <hip/hip_runtime.h>
#include <math.h>

typedef unsigned short ushortT;
typedef __attribute__((ext_vector_type(8))) short bf16x8;
typedef __attribute__((ext_vector_type(4))) float f32x4;

#define NN   512
#define UU   2048
#define VV   43
#define HH   512
#define KMIX 10
#define NCLS 512
#define EPSF 1e-5f
#define KCAT 555     // H + V

// d_out offsets (floats)
#define OFF_DIST  0
#define OFF_H2    262144
#define OFF_H3    524288
#define OFF_PHI   786432
#define OFF_WT    1835008
#define OFF_KAPPA 1857024

__device__ __forceinline__ ushortT f2bf(float f) {
    unsigned int u = __builtin_bit_cast(unsigned int, f);
    u = (u + 0x7fffu + ((u >> 16) & 1u)) >> 16;
    return (ushortT)u;
}

// ---------------------------------------------------------------------------
// Fused attention window: abk -> alpha/beta/kappa -> phi -> wt (cx stream) -> A2.
// One block per n (512 blocks, 2/CU). cx stream uses T14 async staging.
__global__ __launch_bounds__(256) void attn_kernel(
    const float* __restrict__ xt, const float* __restrict__ cx,
    const float* __restrict__ eh, const float* __restrict__ wt_1,
    const float* __restrict__ Ww, const float* __restrict__ Wb,
    const float* __restrict__ kappa_prev,
    float* __restrict__ phi_out, float* __restrict__ wt_out,
    float* __restrict__ kappa_out, ushortT* __restrict__ A2)
{
    __shared__ float x[KCAT];
    __shared__ float sm[32];
    __shared__ float aL[KMIX], bL[KMIX], kL[KMIX];
    __shared__ float phi_lds[UU];
    __shared__ float ch[256*VV];     // 44032 B chunk
    __shared__ float wtv[VV+1];

    int n = blockIdx.x, t = threadIdx.x;
    const float* cxn = cx + (size_t)n*UU*VV;

    // issue chunk 0 loads early: they fly under abk/phi compute
    float4 stg[11];
    {
        const float4* src0 = (const float4*)cxn;
#pragma unroll
        for (int q = 0; q < 11; ++q) { int g = q*256 + t; if (g < 2752) stg[q] = src0[g]; }
    }

    for (int i = t; i < KCAT; i += 256)
        x[i] = (i < HH) ? eh[(size_t)n*HH + i] : wt_1[n*VV + (i - HH)];
    __syncthreads();

    // 30 dots of length 555: 8 lanes per output row
    {
        int g = t >> 3, l = t & 7;
        if (g < 30) {
            const float* w = Ww + (size_t)g*KCAT;
            float v = 0.f;
            for (int i = l; i < KCAT; i += 8) v += x[i]*w[i];
            v += __shfl_xor(v, 4, 64); v += __shfl_xor(v, 2, 64); v += __shfl_xor(v, 1, 64);
            if (l == 0) sm[g] = v;
        }
    }
    __syncthreads();
    if (t < 30) {
        float e = expf(sm[t] + Wb[t]);
        if (t < 10)       aL[t] = e + EPSF;
        else if (t < 20)  bL[t-10] = e + EPSF;
        else { float kap = kappa_prev[n*KMIX + (t-20)] + e; kL[t-20] = kap;
               kappa_out[n*KMIX + (t-20)] = kap; }
    }
    __syncthreads();

    // phi: 8 u per thread (overlaps chunk-0 loads)
#pragma unroll
    for (int i = 0; i < 8; ++i) {
        int u = i*256 + t; float uu = (float)u, s = 0.f;
#pragma unroll
        for (int k = 0; k < KMIX; ++k) { float d = kL[k] - uu; s += aL[k]*expf(-bL[k]*d*d); }
        phi_lds[u] = s;
        phi_out[(size_t)n*UU + u] = s;
    }

    // wt: stream 8 chunks of 256 rows, T14 staged
    float acc[VV];
#pragma unroll
    for (int v = 0; v < VV; ++v) acc[v] = 0.f;
    for (int c = 0; c < 8; ++c) {
        __syncthreads();   // ch free (prev readers done) + phi_lds visible at c=0
#pragma unroll
        for (int q = 0; q < 11; ++q) { int g = q*256 + t; if (g < 2752) ((float4*)ch)[g] = stg[q]; }
        __syncthreads();
        if (c < 7) {
            const float4* src = (const float4*)(cxn + (size_t)(c+1)*256*VV);
#pragma unroll
            for (int q = 0; q < 11; ++q) { int g = q*256 + t; if (g < 2752) stg[q] = src[g]; }
        }
        float p = phi_lds[c*256 + t];
        const float* row = ch + t*VV;      // stride 43 words: conflict-free b32
#pragma unroll
        for (int v = 0; v < VV; ++v) acc[v] += row[v]*p;
    }
    __syncthreads();
    int lane = t & 63, wid = t >> 6;
#pragma unroll
    for (int v = 0; v < VV; ++v) {
        float val = acc[v];
#pragma unroll
        for (int off = 32; off > 0; off >>= 1) val += __shfl_down(val, off, 64);
        if (lane == 0) ch[wid*VV + v] = val;
    }
    __syncthreads();
    if (t < VV) {
        float w4 = ch[t] + ch[VV+t] + ch[2*VV+t] + ch[3*VV+t];
        wt_out[n*VV + t] = w4; wtv[t] = w4;
    }
    __syncthreads();
    if (t < 64) {
        float v = (t == 0) ? xt[n] : (t < 44 ? wtv[t-1] : 0.f);
        A2[(size_t)n*64 + t] = f2bf(v);
    }
}

// ---------------------------------------------------------------------------
// One fused pack: bf16 weight copies + padded W2i + bf16 h2p/h3p rows
__global__ __launch_bounds__(256) void pack_all(
    const float* __restrict__ w2ih, const float* __restrict__ w2hh,
    const float* __restrict__ w3ih, const float* __restrict__ w3hh,
    const float* __restrict__ Yw, const float* __restrict__ h2p, const float* __restrict__ h3p,
    ushortT* __restrict__ W2i, ushortT* __restrict__ W2h,
    ushortT* __restrict__ W3i, ushortT* __restrict__ W3h,
    ushortT* __restrict__ Ywb, ushortT* __restrict__ A2h, ushortT* __restrict__ A3h)
{
    int idx = blockIdx.x*256 + threadIdx.x;
    if (idx < 98304) { int r = idx >> 6, c = idx & 63;
        W2i[idx] = f2bf(c < 44 ? w2ih[r*44 + c] : 0.f); return; }
    idx -= 98304;
    if (idx < 786432) { W2h[idx] = f2bf(w2hh[idx]); return; }
    idx -= 786432;
    if (idx < 786432) { W3i[idx] = f2bf(w3ih[idx]); return; }
    idx -= 786432;
    if (idx < 786432) { W3h[idx] = f2bf(w3hh[idx]); return; }
    idx -= 786432;
    if (idx < 262144) { Ywb[idx] = f2bf(Yw[idx]); return; }
    idx -= 262144;
    if (idx < 262144) { A2h[idx] = f2bf(h2p[idx]); return; }
    idx -= 262144;
    if (idx < 262144) { A3h[idx] = f2bf(h3p[idx]); return; }
}

// ---------------------------------------------------------------------------
// Fused gate-grouped MFMA GEMM + epilogue.
// Block tile: 32 n-rows x 32 j-cols; 4 waves (2m x 2j); wave frag 16x16 x NG gates.
// Two K-phases: (Ai,Wi,NSA*64) then (Ah,Wh,NSB*64). Gate g's W rows = g*512 + j.
// T14 reg-staged global->LDS with both-sides XOR swizzle slot^(row&7).
// EPI: 0 = bias store (dist), 1 = GRU2 (writes h2o + A3i), 2 = GRU3 (writes h3o + Ad)
template<int NG, int NSA, int NSB, int EPI>
__global__ __launch_bounds__(256) void gemm_fused(
    const ushortT* __restrict__ Ai, const ushortT* __restrict__ Wi,
    const ushortT* __restrict__ Ah, const ushortT* __restrict__ Wh,
    const float* __restrict__ bih, const float* __restrict__ bhh,
    const float* __restrict__ hprev, const float* __restrict__ resv,
    float* __restrict__ outF, ushortT* __restrict__ outB, const float* __restrict__ Yb)
{
    constexpr int NS = NSA + NSB;
    __shared__ ushortT lds[(NG+1)*32*64];
    ushortT* lA = lds;
    ushortT* lB = lds + 32*64;

    int tid = threadIdx.x, lane = tid & 63, wid = tid >> 6;
    int wm = wid >> 1, wj = wid & 1;
    int bj0 = blockIdx.x*32, bm0 = blockIdx.y*32;
    int fcol = lane & 15, g2 = lane >> 4;

    float4 stg[NG+1];

    auto loadregs = [&](int s) {
        const ushortT* Ab; const ushortT* Wb_; int K, kb;
        if (s < NSA) { Ab = Ai; Wb_ = Wi; K = NSA*64; kb = s*64; }
        else         { Ab = Ah; Wb_ = Wh; K = NSB*64; kb = (s - NSA)*64; }
        { int row = tid >> 3, slot = tid & 7;
          stg[0] = *(const float4*)(Ab + (size_t)(bm0 + row)*K + kb + slot*8); }
#pragma unroll
        for (int q = 1; q <= NG; ++q) {
            int local = (q-1)*256 + tid;
            int brow = local >> 3, slot = local & 7;
            int gate = brow >> 5, r = brow & 31;
            stg[q] = *(const float4*)(Wb_ + (size_t)(gate*512 + bj0 + r)*K + kb + slot*8);
        }
    };
    auto stowregs = [&]() {
        { int row = tid >> 3, slot = tid & 7;
          *(float4*)(lA + row*64 + (slot ^ (row & 7))*8) = stg[0]; }
#pragma unroll
        for (int q = 1; q <= NG; ++q) {
            int local = (q-1)*256 + tid;
            int brow = local >> 3, slot = local & 7;
            *(float4*)(lB + brow*64 + (slot ^ (brow & 7))*8) = stg[q];
        }
    };

    f32x4 aR = {0.f,0.f,0.f,0.f}, aZ = {0.f,0.f,0.f,0.f};
    f32x4 aN1 = {0.f,0.f,0.f,0.f}, aN2 = {0.f,0.f,0.f,0.f};

    int ra = wm*16 + fcol, rb = wj*16 + fcol;

    loadregs(0);
    for (int s = 0; s < NS; ++s) {
        __syncthreads();
        stowregs();
        __syncthreads();
        if (s + 1 < NS) loadregs(s + 1);

        bf16x8 af0 = *(const bf16x8*)(lA + ra*64 + ((g2     ) ^ (ra & 7))*8);
        bf16x8 af1 = *(const bf16x8*)(lA + ra*64 + ((4 + g2 ) ^ (ra & 7))*8);
#pragma unroll
        for (int g = 0; g < NG; ++g) {
            int rbt = g*32 + rb;
            bf16x8 b0 = *(const bf16x8*)(lB + rbt*64 + ((g2    ) ^ (rbt & 7))*8);
            bf16x8 b1 = *(const bf16x8*)(lB + rbt*64 + ((4 + g2) ^ (rbt & 7))*8);
            if (s < NSA) {
                if (g == 0) { aR  = __builtin_amdgcn_mfma_f32_16x16x32_bf16(af0, b0, aR , 0,0,0);
                              aR  = __builtin_amdgcn_mfma_f32_16x16x32_bf16(af1, b1, aR , 0,0,0); }
                if (g == 1) { aZ  = __builtin_amdgcn_mfma_f32_16x16x32_bf16(af0, b0, aZ , 0,0,0);
                              aZ  = __builtin_amdgcn_mfma_f32_16x16x32_bf16(af1, b1, aZ , 0,0,0); }
                if (g == 2) { aN1 = __builtin_amdgcn_mfma_f32_16x16x32_bf16(af0, b0, aN1, 0,0,0);
                              aN1 = __builtin_amdgcn_mfma_f32_16x16x32_bf16(af1, b1, aN1, 0,0,0); }
            } else {
                if (g == 0) { aR  = __builtin_amdgcn_mfma_f32_16x16x32_bf16(af0, b0, aR , 0,0,0);
                              aR  = __builtin_amdgcn_mfma_f32_16x16x32_bf16(af1, b1, aR , 0,0,0); }
                if (g == 1) { aZ  = __builtin_amdgcn_mfma_f32_16x16x32_bf16(af0, b0, aZ , 0,0,0);
                              aZ  = __builtin_amdgcn_mfma_f32_16x16x32_bf16(af1, b1, aZ , 0,0,0); }
                if (g == 2) { aN2 = __builtin_amdgcn_mfma_f32_16x16x32_bf16(af0, b0, aN2, 0,0,0);
                              aN2 = __builtin_amdgcn_mfma_f32_16x16x32_bf16(af1, b1, aN2, 0,0,0); }
            }
        }
    }

    int row0 = bm0 + wm*16 + (lane >> 4)*4;
    int col  = bj0 + wj*16 + fcol;
    if constexpr (EPI == 0) {
        float b = Yb[col];
#pragma unroll
        for (int e = 0; e < 4; ++e)
            outF[(size_t)(row0 + e)*512 + col] = aR[e] + b;
    } else {
        float b_r  = bih[col] + bhh[col];
        float b_z  = bih[512 + col] + bhh[512 + col];
        float b_ni = bih[1024 + col];
        float b_nh = bhh[1024 + col];
#pragma unroll
        for (int e = 0; e < 4; ++e) {
            size_t off = (size_t)(row0 + e)*512 + col;
            float r  = 1.f/(1.f + expf(-(aR[e] + b_r)));
            float z  = 1.f/(1.f + expf(-(aZ[e] + b_z)));
            float nn = tanhf(aN1[e] + b_ni + r*(aN2[e] + b_nh));
            float h  = (1.f - z)*nn + z*hprev[off];
            outF[off] = h;
            float xo = (EPI == 2) ? (h + resv[off]) : h;
            outB[off] = f2bf(fmaxf(xo, 0.f));
        }
    }
}

// ---------------------------------------------------------------------------
extern "C" void kernel_launch(void* const* d_in, const int* in_sizes, int n_in,
                              void* d_out, int out_size, void* d_ws, size_t ws_size,
                              hipStream_t stream)
{
    const float* xt   = (const float*)d_in[0];
    const float* cx   = (const float*)d_in[1];
    const float* eh   = (const float*)d_in[2];
    const float* wt_1 = (const float*)d_in[3];
    const float* h2p  = (const float*)d_in[4];
    const float* h3p  = (const float*)d_in[5];
    const float* kp   = (const float*)d_in[6];
    const float* Ww   = (const float*)d_in[7];
    const float* Wb   = (const float*)d_in[8];
    const float* w2ih = (const float*)d_in[9];
    const float* w2hh = (const float*)d_in[10];
    const float* b2ih = (const float*)d_in[11];
    const float* b2hh = (const float*)d_in[12];
    const float* w3ih = (const float*)d_in[13];
    const float* w3hh = (const float*)d_in[14];
    const float* b3ih = (const float*)d_in[15];
    const float* b3hh = (const float*)d_in[16];
    const float* Yw   = (const float*)d_in[17];
    const float* Yb   = (const float*)d_in[18];

    float* out = (float*)d_out;
    float* dist = out + OFF_DIST;
    float* h2o  = out + OFF_H2;
    float* h3o  = out + OFF_H3;
    float* phi  = out + OFF_PHI;
    float* wto  = out + OFF_WT;
    float* kapo = out + OFF_KAPPA;

    char* p = (char*)d_ws;
    ushortT* W2i = (ushortT*)p;  p += (size_t)1536*64*2;
    ushortT* W2h = (ushortT*)p;  p += (size_t)1536*512*2;
    ushortT* W3i = (ushortT*)p;  p += (size_t)1536*512*2;
    ushortT* W3h = (ushortT*)p;  p += (size_t)1536*512*2;
    ushortT* Ywb = (ushortT*)p;  p += (size_t)512*512*2;
    ushortT* A2h = (ushortT*)p;  p += (size_t)512*512*2;
    ushortT* A3h = (ushortT*)p;  p += (size_t)512*512*2;
    ushortT* A2  = (ushortT*)p;  p += (size_t)512*64*2;
    ushortT* A3i = (ushortT*)p;  p += (size_t)512*512*2;
    ushortT* Ad  = (ushortT*)p;  p += (size_t)512*512*2;

    attn_kernel<<<NN, 256, 0, stream>>>(xt, cx, eh, wt_1, Ww, Wb, kp, phi, wto, kapo, A2);
    pack_all<<<12672, 256, 0, stream>>>(w2ih, w2hh, w3ih, w3hh, Yw, h2p, h3p,
                                        W2i, W2h, W3i, W3h, Ywb, A2h, A3h);
    // GRU2: gi from [xt|wt] @ w2ih^T (K=64 padded), gh from h2p @ w2hh^T (K=512)
    gemm_fused<3, 1, 8, 1><<<dim3(16, 16), 256, 0, stream>>>(
        A2, W2i, A2h, W2h, b2ih, b2hh, h2p, nullptr, h2o, A3i, nullptr);
    // GRU3: gi from relu(h2) @ w3ih^T, gh from h3p @ w3hh^T
    gemm_fused<3, 8, 8, 2><<<dim3(16, 16), 256, 0, stream>>>(
        A3i, W3i, A3h, W3h, b3ih, b3hh, h3p, h2o, h3o, Ad, nullptr);
    // dist = relu(h3+h2) @ Yw^T + Yb
    gemm_fused<1, 8, 0, 0><<<dim3(16, 16), 256, 0, stream>>>(
        Ad, Ywb, nullptr, nullptr, nullptr, nullptr, nullptr, nullptr, dist, nullptr, Yb);
}

// Round 4
// 179.109 us; speedup vs baseline: 1.0666x; 1.0666x over previous
//
#include <hip/hip_runtime.h>
#include <math.h>

typedef unsigned short ushortT;
typedef __attribute__((ext_vector_type(8))) short bf16x8;
typedef __attribute__((ext_vector_type(4))) float f32x4;

#define NN   512
#define UU   2048
#define VV   43
#define HH   512
#define KMIX 10
#define NCLS 512
#define EPSF 1e-5f
#define KCAT 555     // H + V

// d_out offsets (floats)
#define OFF_DIST  0
#define OFF_H2    262144
#define OFF_H3    524288
#define OFF_PHI   786432
#define OFF_WT    1835008
#define OFF_KAPPA 1857024

__device__ __forceinline__ ushortT f2bf(float f) {
    unsigned int u = __builtin_bit_cast(unsigned int, f);
    u = (u + 0x7fffu + ((u >> 16) & 1u)) >> 16;
    return (ushortT)u;
}

__device__ __forceinline__ void gld_lds16(const float* g, float* l) {
    __builtin_amdgcn_global_load_lds(
        (const __attribute__((address_space(1))) void*)g,
        (__attribute__((address_space(3))) void*)l,
        16, 0, 0);
}

// ---------------------------------------------------------------------------
// Fused attention window: abk -> alpha/beta/kappa -> phi -> wt (cx stream) -> A2.
// One block per n. cx streamed HBM->LDS via global_load_lds, per-wave regions,
// double-buffered, counted vmcnt waits (no barrier in the stream loop).
// Wave w owns float4-groups [w*688,(w+1)*688) of each 256-row chunk; thread t
// consumes row t, which lies inside its own wave's region.
__global__ __launch_bounds__(256) void attn_kernel(
    const float* __restrict__ xt, const float* __restrict__ cx,
    const float* __restrict__ eh, const float* __restrict__ wt_1,
    const float* __restrict__ Ww, const float* __restrict__ Wb,
    const float* __restrict__ kappa_prev,
    float* __restrict__ phi_out, float* __restrict__ wt_out,
    float* __restrict__ kappa_out, ushortT* __restrict__ A2)
{
    __shared__ float x[KCAT];
    __shared__ float sm[32];
    __shared__ float aL[KMIX], bL[KMIX], kL[KMIX];
    __shared__ float phi_lds[UU];
    __shared__ __align__(16) float ch[2][256*VV];   // 2 x 44032 B
    __shared__ float wtv[VV+1];

    int n = blockIdx.x, t = threadIdx.x;
    int lane = t & 63, wid = t >> 6;
    const float* cxn = cx + (size_t)n*UU*VV;

    // issue chunk c's loads for this wave (11 VMEM ops/wave, last 48 lanes)
    auto issue_chunk = [&](int c) {
        const float* gbase = cxn + (size_t)c*256*VV;
        float* lbase = &ch[c & 1][0];
#pragma unroll
        for (int q = 0; q < 11; ++q) {
            int g = wid*688 + q*64 + lane;
            if (q < 10 || lane < 48)
                gld_lds16(gbase + (size_t)g*4, lbase + (size_t)g*4);
        }
    };

    issue_chunk(0);
    issue_chunk(1);

    // ---- abk: 30 dots of length 555 (overlaps chunk 0/1 flight) ----
    for (int i = t; i < KCAT; i += 256)
        x[i] = (i < HH) ? eh[(size_t)n*HH + i] : wt_1[n*VV + (i - HH)];
    __syncthreads();
    {
        int g = t >> 3, l = t & 7;
        if (g < 30) {
            const float* w = Ww + (size_t)g*KCAT;
            float v = 0.f;
            for (int i = l; i < KCAT; i += 8) v += x[i]*w[i];
            v += __shfl_xor(v, 4, 64); v += __shfl_xor(v, 2, 64); v += __shfl_xor(v, 1, 64);
            if (l == 0) sm[g] = v;
        }
    }
    __syncthreads();
    if (t < 30) {
        float e = expf(sm[t] + Wb[t]);
        if (t < 10)       aL[t] = e + EPSF;
        else if (t < 20)  bL[t-10] = e + EPSF;
        else { float kap = kappa_prev[n*KMIX + (t-20)] + e; kL[t-20] = kap;
               kappa_out[n*KMIX + (t-20)] = kap; }
    }
    __syncthreads();

    // ---- phi: thread t owns u = i*256+t (self-consumed later, no barrier) ----
#pragma unroll
    for (int i = 0; i < 8; ++i) {
        int u = i*256 + t; float uu = (float)u, s = 0.f;
#pragma unroll
        for (int k = 0; k < KMIX; ++k) { float d = kL[k] - uu; s += aL[k]*expf(-bL[k]*d*d); }
        phi_lds[u] = s;
    }

    // ---- stream: 8 chunks, double-buffered, per-wave independent ----
    float acc[VV];
#pragma unroll
    for (int v = 0; v < VV; ++v) acc[v] = 0.f;
    for (int c = 0; c < 8; ++c) {
        if (c < 7) asm volatile("s_waitcnt vmcnt(11)" ::: "memory");
        else       asm volatile("s_waitcnt vmcnt(0)"  ::: "memory");
        __builtin_amdgcn_sched_barrier(0);
        float p = phi_lds[c*256 + t];
        const float* row = &ch[c & 1][0] + t*VV;   // stride-43 words: 2-way, free
#pragma unroll
        for (int v = 0; v < VV; ++v) acc[v] += row[v]*p;
        if (c + 2 < 8) {
            asm volatile("s_waitcnt lgkmcnt(0)" ::: "memory");  // ds_reads done before overwrite
            __builtin_amdgcn_sched_barrier(0);
            issue_chunk(c + 2);
        }
    }

    // ---- reduce 256 threads -> wt[43] ----
    __syncthreads();   // all waves done consuming before ch[0] reuse
#pragma unroll
    for (int v = 0; v < VV; ++v) {
        float val = acc[v];
#pragma unroll
        for (int off = 32; off > 0; off >>= 1) val += __shfl_down(val, off, 64);
        if (lane == 0) ch[0][wid*VV + v] = val;
    }
    __syncthreads();
    if (t < VV) {
        float w4 = ch[0][t] + ch[0][VV+t] + ch[0][2*VV+t] + ch[0][3*VV+t];
        wt_out[n*VV + t] = w4; wtv[t] = w4;
    }
    __syncthreads();
    if (t < 64) {
        float v = (t == 0) ? xt[n] : (t < 44 ? wtv[t-1] : 0.f);
        A2[(size_t)n*64 + t] = f2bf(v);
    }
#pragma unroll
    for (int i = 0; i < 8; ++i)
        phi_out[(size_t)n*UU + i*256 + t] = phi_lds[i*256 + t];
}

// ---------------------------------------------------------------------------
// One fused pack: bf16 weight copies + padded W2i + bf16 h2p/h3p rows
__global__ __launch_bounds__(256) void pack_all(
    const float* __restrict__ w2ih, const float* __restrict__ w2hh,
    const float* __restrict__ w3ih, const float* __restrict__ w3hh,
    const float* __restrict__ Yw, const float* __restrict__ h2p, const float* __restrict__ h3p,
    ushortT* __restrict__ W2i, ushortT* __restrict__ W2h,
    ushortT* __restrict__ W3i, ushortT* __restrict__ W3h,
    ushortT* __restrict__ Ywb, ushortT* __restrict__ A2h, ushortT* __restrict__ A3h)
{
    int idx = blockIdx.x*256 + threadIdx.x;
    if (idx < 98304) { int r = idx >> 6, c = idx & 63;
        W2i[idx] = f2bf(c < 44 ? w2ih[r*44 + c] : 0.f); return; }
    idx -= 98304;
    if (idx < 786432) { W2h[idx] = f2bf(w2hh[idx]); return; }
    idx -= 786432;
    if (idx < 786432) { W3i[idx] = f2bf(w3ih[idx]); return; }
    idx -= 786432;
    if (idx < 786432) { W3h[idx] = f2bf(w3hh[idx]); return; }
    idx -= 786432;
    if (idx < 262144) { Ywb[idx] = f2bf(Yw[idx]); return; }
    idx -= 262144;
    if (idx < 262144) { A2h[idx] = f2bf(h2p[idx]); return; }
    idx -= 262144;
    if (idx < 262144) { A3h[idx] = f2bf(h3p[idx]); return; }
}

// ---------------------------------------------------------------------------
// Fused gate-grouped MFMA GEMM + epilogue (unchanged from R3, validated).
template<int NG, int NSA, int NSB, int EPI>
__global__ __launch_bounds__(256) void gemm_fused(
    const ushortT* __restrict__ Ai, const ushortT* __restrict__ Wi,
    const ushortT* __restrict__ Ah, const ushortT* __restrict__ Wh,
    const float* __restrict__ bih, const float* __restrict__ bhh,
    const float* __restrict__ hprev, const float* __restrict__ resv,
    float* __restrict__ outF, ushortT* __restrict__ outB, const float* __restrict__ Yb)
{
    constexpr int NS = NSA + NSB;
    __shared__ ushortT lds[(NG+1)*32*64];
    ushortT* lA = lds;
    ushortT* lB = lds + 32*64;

    int tid = threadIdx.x, lane = tid & 63, wid = tid >> 6;
    int wm = wid >> 1, wj = wid & 1;
    int bj0 = blockIdx.x*32, bm0 = blockIdx.y*32;
    int fcol = lane & 15, g2 = lane >> 4;

    float4 stg[NG+1];

    auto loadregs = [&](int s) {
        const ushortT* Ab; const ushortT* Wb_; int K, kb;
        if (s < NSA) { Ab = Ai; Wb_ = Wi; K = NSA*64; kb = s*64; }
        else         { Ab = Ah; Wb_ = Wh; K = NSB*64; kb = (s - NSA)*64; }
        { int row = tid >> 3, slot = tid & 7;
          stg[0] = *(const float4*)(Ab + (size_t)(bm0 + row)*K + kb + slot*8); }
#pragma unroll
        for (int q = 1; q <= NG; ++q) {
            int local = (q-1)*256 + tid;
            int brow = local >> 3, slot = local & 7;
            int gate = brow >> 5, r = brow & 31;
            stg[q] = *(const float4*)(Wb_ + (size_t)(gate*512 + bj0 + r)*K + kb + slot*8);
        }
    };
    auto stowregs = [&]() {
        { int row = tid >> 3, slot = tid & 7;
          *(float4*)(lA + row*64 + (slot ^ (row & 7))*8) = stg[0]; }
#pragma unroll
        for (int q = 1; q <= NG; ++q) {
            int local = (q-1)*256 + tid;
            int brow = local >> 3, slot = local & 7;
            *(float4*)(lB + brow*64 + (slot ^ (brow & 7))*8) = stg[q];
        }
    };

    f32x4 aR = {0.f,0.f,0.f,0.f}, aZ = {0.f,0.f,0.f,0.f};
    f32x4 aN1 = {0.f,0.f,0.f,0.f}, aN2 = {0.f,0.f,0.f,0.f};

    int ra = wm*16 + fcol, rb = wj*16 + fcol;

    loadregs(0);
    for (int s = 0; s < NS; ++s) {
        __syncthreads();
        stowregs();
        __syncthreads();
        if (s + 1 < NS) loadregs(s + 1);

        bf16x8 af0 = *(const bf16x8*)(lA + ra*64 + ((g2     ) ^ (ra & 7))*8);
        bf16x8 af1 = *(const bf16x8*)(lA + ra*64 + ((4 + g2 ) ^ (ra & 7))*8);
#pragma unroll
        for (int g = 0; g < NG; ++g) {
            int rbt = g*32 + rb;
            bf16x8 b0 = *(const bf16x8*)(lB + rbt*64 + ((g2    ) ^ (rbt & 7))*8);
            bf16x8 b1 = *(const bf16x8*)(lB + rbt*64 + ((4 + g2) ^ (rbt & 7))*8);
            if (s < NSA) {
                if (g == 0) { aR  = __builtin_amdgcn_mfma_f32_16x16x32_bf16(af0, b0, aR , 0,0,0);
                              aR  = __builtin_amdgcn_mfma_f32_16x16x32_bf16(af1, b1, aR , 0,0,0); }
                if (g == 1) { aZ  = __builtin_amdgcn_mfma_f32_16x16x32_bf16(af0, b0, aZ , 0,0,0);
                              aZ  = __builtin_amdgcn_mfma_f32_16x16x32_bf16(af1, b1, aZ , 0,0,0); }
                if (g == 2) { aN1 = __builtin_amdgcn_mfma_f32_16x16x32_bf16(af0, b0, aN1, 0,0,0);
                              aN1 = __builtin_amdgcn_mfma_f32_16x16x32_bf16(af1, b1, aN1, 0,0,0); }
            } else {
                if (g == 0) { aR  = __builtin_amdgcn_mfma_f32_16x16x32_bf16(af0, b0, aR , 0,0,0);
                              aR  = __builtin_amdgcn_mfma_f32_16x16x32_bf16(af1, b1, aR , 0,0,0); }
                if (g == 1) { aZ  = __builtin_amdgcn_mfma_f32_16x16x32_bf16(af0, b0, aZ , 0,0,0);
                              aZ  = __builtin_amdgcn_mfma_f32_16x16x32_bf16(af1, b1, aZ , 0,0,0); }
                if (g == 2) { aN2 = __builtin_amdgcn_mfma_f32_16x16x32_bf16(af0, b0, aN2, 0,0,0);
                              aN2 = __builtin_amdgcn_mfma_f32_16x16x32_bf16(af1, b1, aN2, 0,0,0); }
            }
        }
    }

    int row0 = bm0 + wm*16 + (lane >> 4)*4;
    int col  = bj0 + wj*16 + fcol;
    if constexpr (EPI == 0) {
        float b = Yb[col];
#pragma unroll
        for (int e = 0; e < 4; ++e)
            outF[(size_t)(row0 + e)*512 + col] = aR[e] + b;
    } else {
        float b_r  = bih[col] + bhh[col];
        float b_z  = bih[512 + col] + bhh[512 + col];
        float b_ni = bih[1024 + col];
        float b_nh = bhh[1024 + col];
#pragma unroll
        for (int e = 0; e < 4; ++e) {
            size_t off = (size_t)(row0 + e)*512 + col;
            float r  = 1.f/(1.f + expf(-(aR[e] + b_r)));
            float z  = 1.f/(1.f + expf(-(aZ[e] + b_z)));
            float nn = tanhf(aN1[e] + b_ni + r*(aN2[e] + b_nh));
            float h  = (1.f - z)*nn + z*hprev[off];
            outF[off] = h;
            float xo = (EPI == 2) ? (h + resv[off]) : h;
            outB[off] = f2bf(fmaxf(xo, 0.f));
        }
    }
}

// ---------------------------------------------------------------------------
extern "C" void kernel_launch(void* const* d_in, const int* in_sizes, int n_in,
                              void* d_out, int out_size, void* d_ws, size_t ws_size,
                              hipStream_t stream)
{
    const float* xt   = (const float*)d_in[0];
    const float* cx   = (const float*)d_in[1];
    const float* eh   = (const float*)d_in[2];
    const float* wt_1 = (const float*)d_in[3];
    const float* h2p  = (const float*)d_in[4];
    const float* h3p  = (const float*)d_in[5];
    const float* kp   = (const float*)d_in[6];
    const float* Ww   = (const float*)d_in[7];
    const float* Wb   = (const float*)d_in[8];
    const float* w2ih = (const float*)d_in[9];
    const float* w2hh = (const float*)d_in[10];
    const float* b2ih = (const float*)d_in[11];
    const float* b2hh = (const float*)d_in[12];
    const float* w3ih = (const float*)d_in[13];
    const float* w3hh = (const float*)d_in[14];
    const float* b3ih = (const float*)d_in[15];
    const float* b3hh = (const float*)d_in[16];
    const float* Yw   = (const float*)d_in[17];
    const float* Yb   = (const float*)d_in[18];

    float* out = (float*)d_out;
    float* dist = out + OFF_DIST;
    float* h2o  = out + OFF_H2;
    float* h3o  = out + OFF_H3;
    float* phi  = out + OFF_PHI;
    float* wto  = out + OFF_WT;
    float* kapo = out + OFF_KAPPA;

    char* p = (char*)d_ws;
    ushortT* W2i = (ushortT*)p;  p += (size_t)1536*64*2;
    ushortT* W2h = (ushortT*)p;  p += (size_t)1536*512*2;
    ushortT* W3i = (ushortT*)p;  p += (size_t)1536*512*2;
    ushortT* W3h = (ushortT*)p;  p += (size_t)1536*512*2;
    ushortT* Ywb = (ushortT*)p;  p += (size_t)512*512*2;
    ushortT* A2h = (ushortT*)p;  p += (size_t)512*512*2;
    ushortT* A3h = (ushortT*)p;  p += (size_t)512*512*2;
    ushortT* A2  = (ushortT*)p;  p += (size_t)512*64*2;
    ushortT* A3i = (ushortT*)p;  p += (size_t)512*512*2;
    ushortT* Ad  = (ushortT*)p;  p += (size_t)512*512*2;

    attn_kernel<<<NN, 256, 0, stream>>>(xt, cx, eh, wt_1, Ww, Wb, kp, phi, wto, kapo, A2);
    pack_all<<<12672, 256, 0, stream>>>(w2ih, w2hh, w3ih, w3hh, Yw, h2p, h3p,
                                        W2i, W2h, W3i, W3h, Ywb, A2h, A3h);
    // GRU2: gi from [xt|wt] @ w2ih^T (K=64 padded), gh from h2p @ w2hh^T (K=512)
    gemm_fused<3, 1, 8, 1><<<dim3(16, 16), 256, 0, stream>>>(
        A2, W2i, A2h, W2h, b2ih, b2hh, h2p, nullptr, h2o, A3i, nullptr);
    // GRU3: gi from relu(h2) @ w3ih^T, gh from h3p @ w3hh^T
    gemm_fused<3, 8, 8, 2><<<dim3(16, 16), 256, 0, stream>>>(
        A3i, W3i, A3h, W3h, b3ih, b3hh, h3p, h2o, h3o, Ad, nullptr);
    // dist = relu(h3+h2) @ Yw^T + Yb
    gemm_fused<1, 8, 0, 0><<<dim3(16, 16), 256, 0, stream>>>(
        Ad, Ywb, nullptr, nullptr, nullptr, nullptr, nullptr, nullptr, dist, nullptr, Yb);
}

// Round 5
// 126.891 us; speedup vs baseline: 1.5056x; 1.4115x over previous
//
#include <hip/hip_runtime.h>
#include <math.h>

typedef unsigned short ushortT;
typedef __attribute__((ext_vector_type(8))) short bf16x8;
typedef __attribute__((ext_vector_type(4))) float f32x4;
typedef float f32x4u __attribute__((ext_vector_type(4), aligned(4)));  // 4B-aligned vec load

#define NN   512
#define UU   2048
#define VV   43
#define HH   512
#define KMIX 10
#define NCLS 512
#define EPSF 1e-5f
#define KCAT 555     // H + V

// d_out offsets (floats)
#define OFF_DIST  0
#define OFF_H2    262144
#define OFF_H3    524288
#define OFF_PHI   786432
#define OFF_WT    1835008
#define OFF_KAPPA 1857024

__device__ __forceinline__ ushortT f2bf(float f) {
    unsigned int u = __builtin_bit_cast(unsigned int, f);
    u = (u + 0x7fffu + ((u >> 16) & 1u)) >> 16;
    return (ushortT)u;
}

// ---------------------------------------------------------------------------
// Fused attention window: abk -> alpha/beta/kappa -> phi (exact, all u) ->
// wt = sum_u cx[u,:]*phi[u], truncated at the exact numeric support of phi:
// for u > kappa_k + sqrt((60+ln alpha_k)/beta_k) every term < e^-60 (f32 zero;
// contribution to wt < 1e-20 vs thresholds ~6.9). Row-per-thread VGPR loads.
__global__ __launch_bounds__(256, 2) void attn_kernel(
    const float* __restrict__ xt, const float* __restrict__ cx,
    const float* __restrict__ eh, const float* __restrict__ wt_1,
    const float* __restrict__ Ww, const float* __restrict__ Wb,
    const float* __restrict__ kappa_prev,
    float* __restrict__ phi_out, float* __restrict__ wt_out,
    float* __restrict__ kappa_out, ushortT* __restrict__ A2)
{
    __shared__ float x[KCAT];
    __shared__ float sm[32];
    __shared__ float aL[KMIX], bL[KMIX], kL[KMIX], um[KMIX];
    __shared__ float red[4*VV];
    __shared__ float wtv[VV+1];

    int n = blockIdx.x, t = threadIdx.x;
    int lane = t & 63, wid = t >> 6;
    const float* cxn = cx + (size_t)n*UU*VV;

    // ---- abk: 30 dots of length 555 ----
    for (int i = t; i < KCAT; i += 256)
        x[i] = (i < HH) ? eh[(size_t)n*HH + i] : wt_1[n*VV + (i - HH)];
    __syncthreads();
    {
        int g = t >> 3, l = t & 7;
        if (g < 30) {
            const float* w = Ww + (size_t)g*KCAT;
            float v = 0.f;
            for (int i = l; i < KCAT; i += 8) v += x[i]*w[i];
            v += __shfl_xor(v, 4, 64); v += __shfl_xor(v, 2, 64); v += __shfl_xor(v, 1, 64);
            if (l == 0) sm[g] = v;
        }
    }
    __syncthreads();
    if (t < 30) {
        float e = expf(sm[t] + Wb[t]);
        if (t < 10)       aL[t] = e + EPSF;
        else if (t < 20)  bL[t-10] = e + EPSF;
        else { float kap = kappa_prev[n*KMIX + (t-20)] + e; kL[t-20] = kap;
               kappa_out[n*KMIX + (t-20)] = kap; }
    }
    __syncthreads();
    // per-k numeric support end: kappa + sqrt(max(60 + ln(alpha), 0)/beta)
    if (t < KMIX)
        um[t] = kL[t] + sqrtf(fmaxf(60.f + logf(aL[t]), 0.f) / bL[t]);
    __syncthreads();
    float ulim = um[0];
#pragma unroll
    for (int k = 1; k < KMIX; ++k) ulim = fmaxf(ulim, um[k]);
    int nchunks = min(8, (int)(ulim) / 256 + 1);
    nchunks = __builtin_amdgcn_readfirstlane(nchunks);

    // ---- phi: exact for all u; thread t owns u = c*256+t ----
    float phi_reg[8];
#pragma unroll
    for (int c = 0; c < 8; ++c) {
        int u = c*256 + t; float uu = (float)u, s = 0.f;
#pragma unroll
        for (int k = 0; k < KMIX; ++k) { float d = kL[k] - uu; s += aL[k]*expf(-bL[k]*d*d); }
        phi_reg[c] = s;
        phi_out[(size_t)n*UU + u] = s;
    }

    // ---- wt: stream only live chunks, row-per-thread direct loads ----
    float acc[VV];
#pragma unroll
    for (int v = 0; v < VV; ++v) acc[v] = 0.f;
#pragma unroll
    for (int c = 0; c < 8; ++c) {
        if (c < nchunks) {
            const float* rowp = cxn + (size_t)(c*256 + t)*VV;
            f32x4u r[10];
#pragma unroll
            for (int q = 0; q < 10; ++q) r[q] = *(const f32x4u*)(rowp + q*4);
            f32x4u rt = *(const f32x4u*)(rowp + 39);   // covers v=39..42
            float p = phi_reg[c];
#pragma unroll
            for (int q = 0; q < 10; ++q) {
                acc[q*4+0] += r[q].x*p; acc[q*4+1] += r[q].y*p;
                acc[q*4+2] += r[q].z*p; acc[q*4+3] += r[q].w*p;
            }
            acc[40] += rt.y*p; acc[41] += rt.z*p; acc[42] += rt.w*p;
        }
    }

    // ---- reduce 256 threads -> wt[43] ----
#pragma unroll
    for (int v = 0; v < VV; ++v) {
        float val = acc[v];
#pragma unroll
        for (int off = 32; off > 0; off >>= 1) val += __shfl_down(val, off, 64);
        if (lane == 0) red[wid*VV + v] = val;
    }
    __syncthreads();
    if (t < VV) {
        float w4 = red[t] + red[VV+t] + red[2*VV+t] + red[3*VV+t];
        wt_out[n*VV + t] = w4; wtv[t] = w4;
    }
    __syncthreads();
    if (t < 64) {
        float v = (t == 0) ? xt[n] : (t < 44 ? wtv[t-1] : 0.f);
        A2[(size_t)n*64 + t] = f2bf(v);
    }
}

// ---------------------------------------------------------------------------
// One fused pack: bf16 weight copies + padded W2i + bf16 h2p/h3p rows
__global__ __launch_bounds__(256) void pack_all(
    const float* __restrict__ w2ih, const float* __restrict__ w2hh,
    const float* __restrict__ w3ih, const float* __restrict__ w3hh,
    const float* __restrict__ Yw, const float* __restrict__ h2p, const float* __restrict__ h3p,
    ushortT* __restrict__ W2i, ushortT* __restrict__ W2h,
    ushortT* __restrict__ W3i, ushortT* __restrict__ W3h,
    ushortT* __restrict__ Ywb, ushortT* __restrict__ A2h, ushortT* __restrict__ A3h)
{
    int idx = blockIdx.x*256 + threadIdx.x;
    if (idx < 98304) { int r = idx >> 6, c = idx & 63;
        W2i[idx] = f2bf(c < 44 ? w2ih[r*44 + c] : 0.f); return; }
    idx -= 98304;
    if (idx < 786432) { W2h[idx] = f2bf(w2hh[idx]); return; }
    idx -= 786432;
    if (idx < 786432) { W3i[idx] = f2bf(w3ih[idx]); return; }
    idx -= 786432;
    if (idx < 786432) { W3h[idx] = f2bf(w3hh[idx]); return; }
    idx -= 786432;
    if (idx < 262144) { Ywb[idx] = f2bf(Yw[idx]); return; }
    idx -= 262144;
    if (idx < 262144) { A2h[idx] = f2bf(h2p[idx]); return; }
    idx -= 262144;
    if (idx < 262144) { A3h[idx] = f2bf(h3p[idx]); return; }
}

// ---------------------------------------------------------------------------
// Fused gate-grouped MFMA GEMM + epilogue (unchanged, validated R3/R4).
template<int NG, int NSA, int NSB, int EPI>
__global__ __launch_bounds__(256) void gemm_fused(
    const ushortT* __restrict__ Ai, const ushortT* __restrict__ Wi,
    const ushortT* __restrict__ Ah, const ushortT* __restrict__ Wh,
    const float* __restrict__ bih, const float* __restrict__ bhh,
    const float* __restrict__ hprev, const float* __restrict__ resv,
    float* __restrict__ outF, ushortT* __restrict__ outB, const float* __restrict__ Yb)
{
    constexpr int NS = NSA + NSB;
    __shared__ ushortT lds[(NG+1)*32*64];
    ushortT* lA = lds;
    ushortT* lB = lds + 32*64;

    int tid = threadIdx.x, lane = tid & 63, wid = tid >> 6;
    int wm = wid >> 1, wj = wid & 1;
    int bj0 = blockIdx.x*32, bm0 = blockIdx.y*32;
    int fcol = lane & 15, g2 = lane >> 4;

    float4 stg[NG+1];

    auto loadregs = [&](int s) {
        const ushortT* Ab; const ushortT* Wb_; int K, kb;
        if (s < NSA) { Ab = Ai; Wb_ = Wi; K = NSA*64; kb = s*64; }
        else         { Ab = Ah; Wb_ = Wh; K = NSB*64; kb = (s - NSA)*64; }
        { int row = tid >> 3, slot = tid & 7;
          stg[0] = *(const float4*)(Ab + (size_t)(bm0 + row)*K + kb + slot*8); }
#pragma unroll
        for (int q = 1; q <= NG; ++q) {
            int local = (q-1)*256 + tid;
            int brow = local >> 3, slot = local & 7;
            int gate = brow >> 5, r = brow & 31;
            stg[q] = *(const float4*)(Wb_ + (size_t)(gate*512 + bj0 + r)*K + kb + slot*8);
        }
    };
    auto stowregs = [&]() {
        { int row = tid >> 3, slot = tid & 7;
          *(float4*)(lA + row*64 + (slot ^ (row & 7))*8) = stg[0]; }
#pragma unroll
        for (int q = 1; q <= NG; ++q) {
            int local = (q-1)*256 + tid;
            int brow = local >> 3, slot = local & 7;
            *(float4*)(lB + brow*64 + (slot ^ (brow & 7))*8) = stg[q];
        }
    };

    f32x4 aR = {0.f,0.f,0.f,0.f}, aZ = {0.f,0.f,0.f,0.f};
    f32x4 aN1 = {0.f,0.f,0.f,0.f}, aN2 = {0.f,0.f,0.f,0.f};

    int ra = wm*16 + fcol, rb = wj*16 + fcol;

    loadregs(0);
    for (int s = 0; s < NS; ++s) {
        __syncthreads();
        stowregs();
        __syncthreads();
        if (s + 1 < NS) loadregs(s + 1);

        bf16x8 af0 = *(const bf16x8*)(lA + ra*64 + ((g2     ) ^ (ra & 7))*8);
        bf16x8 af1 = *(const bf16x8*)(lA + ra*64 + ((4 + g2 ) ^ (ra & 7))*8);
#pragma unroll
        for (int g = 0; g < NG; ++g) {
            int rbt = g*32 + rb;
            bf16x8 b0 = *(const bf16x8*)(lB + rbt*64 + ((g2    ) ^ (rbt & 7))*8);
            bf16x8 b1 = *(const bf16x8*)(lB + rbt*64 + ((4 + g2) ^ (rbt & 7))*8);
            if (s < NSA) {
                if (g == 0) { aR  = __builtin_amdgcn_mfma_f32_16x16x32_bf16(af0, b0, aR , 0,0,0);
                              aR  = __builtin_amdgcn_mfma_f32_16x16x32_bf16(af1, b1, aR , 0,0,0); }
                if (g == 1) { aZ  = __builtin_amdgcn_mfma_f32_16x16x32_bf16(af0, b0, aZ , 0,0,0);
                              aZ  = __builtin_amdgcn_mfma_f32_16x16x32_bf16(af1, b1, aZ , 0,0,0); }
                if (g == 2) { aN1 = __builtin_amdgcn_mfma_f32_16x16x32_bf16(af0, b0, aN1, 0,0,0);
                              aN1 = __builtin_amdgcn_mfma_f32_16x16x32_bf16(af1, b1, aN1, 0,0,0); }
            } else {
                if (g == 0) { aR  = __builtin_amdgcn_mfma_f32_16x16x32_bf16(af0, b0, aR , 0,0,0);
                              aR  = __builtin_amdgcn_mfma_f32_16x16x32_bf16(af1, b1, aR , 0,0,0); }
                if (g == 1) { aZ  = __builtin_amdgcn_mfma_f32_16x16x32_bf16(af0, b0, aZ , 0,0,0);
                              aZ  = __builtin_amdgcn_mfma_f32_16x16x32_bf16(af1, b1, aZ , 0,0,0); }
                if (g == 2) { aN2 = __builtin_amdgcn_mfma_f32_16x16x32_bf16(af0, b0, aN2, 0,0,0);
                              aN2 = __builtin_amdgcn_mfma_f32_16x16x32_bf16(af1, b1, aN2, 0,0,0); }
            }
        }
    }

    int row0 = bm0 + wm*16 + (lane >> 4)*4;
    int col  = bj0 + wj*16 + fcol;
    if constexpr (EPI == 0) {
        float b = Yb[col];
#pragma unroll
        for (int e = 0; e < 4; ++e)
            outF[(size_t)(row0 + e)*512 + col] = aR[e] + b;
    } else {
        float b_r  = bih[col] + bhh[col];
        float b_z  = bih[512 + col] + bhh[512 + col];
        float b_ni = bih[1024 + col];
        float b_nh = bhh[1024 + col];
#pragma unroll
        for (int e = 0; e < 4; ++e) {
            size_t off = (size_t)(row0 + e)*512 + col;
            float r  = 1.f/(1.f + expf(-(aR[e] + b_r)));
            float z  = 1.f/(1.f + expf(-(aZ[e] + b_z)));
            float nn = tanhf(aN1[e] + b_ni + r*(aN2[e] + b_nh));
            float h  = (1.f - z)*nn + z*hprev[off];
            outF[off] = h;
            float xo = (EPI == 2) ? (h + resv[off]) : h;
            outB[off] = f2bf(fmaxf(xo, 0.f));
        }
    }
}

// ---------------------------------------------------------------------------
extern "C" void kernel_launch(void* const* d_in, const int* in_sizes, int n_in,
                              void* d_out, int out_size, void* d_ws, size_t ws_size,
                              hipStream_t stream)
{
    const float* xt   = (const float*)d_in[0];
    const float* cx   = (const float*)d_in[1];
    const float* eh   = (const float*)d_in[2];
    const float* wt_1 = (const float*)d_in[3];
    const float* h2p  = (const float*)d_in[4];
    const float* h3p  = (const float*)d_in[5];
    const float* kp   = (const float*)d_in[6];
    const float* Ww   = (const float*)d_in[7];
    const float* Wb   = (const float*)d_in[8];
    const float* w2ih = (const float*)d_in[9];
    const float* w2hh = (const float*)d_in[10];
    const float* b2ih = (const float*)d_in[11];
    const float* b2hh = (const float*)d_in[12];
    const float* w3ih = (const float*)d_in[13];
    const float* w3hh = (const float*)d_in[14];
    const float* b3ih = (const float*)d_in[15];
    const float* b3hh = (const float*)d_in[16];
    const float* Yw   = (const float*)d_in[17];
    const float* Yb   = (const float*)d_in[18];

    float* out = (float*)d_out;
    float* dist = out + OFF_DIST;
    float* h2o  = out + OFF_H2;
    float* h3o  = out + OFF_H3;
    float* phi  = out + OFF_PHI;
    float* wto  = out + OFF_WT;
    float* kapo = out + OFF_KAPPA;

    char* p = (char*)d_ws;
    ushortT* W2i = (ushortT*)p;  p += (size_t)1536*64*2;
    ushortT* W2h = (ushortT*)p;  p += (size_t)1536*512*2;
    ushortT* W3i = (ushortT*)p;  p += (size_t)1536*512*2;
    ushortT* W3h = (ushortT*)p;  p += (size_t)1536*512*2;
    ushortT* Ywb = (ushortT*)p;  p += (size_t)512*512*2;
    ushortT* A2h = (ushortT*)p;  p += (size_t)512*512*2;
    ushortT* A3h = (ushortT*)p;  p += (size_t)512*512*2;
    ushortT* A2  = (ushortT*)p;  p += (size_t)512*64*2;
    ushortT* A3i = (ushortT*)p;  p += (size_t)512*512*2;
    ushortT* Ad  = (ushortT*)p;  p += (size_t)512*512*2;

    attn_kernel<<<NN, 256, 0, stream>>>(xt, cx, eh, wt_1, Ww, Wb, kp, phi, wto, kapo, A2);
    pack_all<<<12672, 256, 0, stream>>>(w2ih, w2hh, w3ih, w3hh, Yw, h2p, h3p,
                                        W2i, W2h, W3i, W3h, Ywb, A2h, A3h);
    // GRU2: gi from [xt|wt] @ w2ih^T (K=64 padded), gh from h2p @ w2hh^T (K=512)
    gemm_fused<3, 1, 8, 1><<<dim3(16, 16), 256, 0, stream>>>(
        A2, W2i, A2h, W2h, b2ih, b2hh, h2p, nullptr, h2o, A3i, nullptr);
    // GRU3: gi from relu(h2) @ w3ih^T, gh from h3p @ w3hh^T
    gemm_fused<3, 8, 8, 2><<<dim3(16, 16), 256, 0, stream>>>(
        A3i, W3i, A3h, W3h, b3ih, b3hh, h3p, h2o, h3o, Ad, nullptr);
    // dist = relu(h3+h2) @ Yw^T + Yb
    gemm_fused<1, 8, 0, 0><<<dim3(16, 16), 256, 0, stream>>>(
        Ad, Ywb, nullptr, nullptr, nullptr, nullptr, nullptr, nullptr, dist, nullptr, Yb);
}

// Round 6
// 80.378 us; speedup vs baseline: 2.3768x; 1.5787x over previous
//
#include <hip/hip_runtime.h>
#include <math.h>

typedef unsigned short ushortT;
typedef __attribute__((ext_vector_type(8))) short bf16x8;
typedef __attribute__((ext_vector_type(4))) float f32x4;
typedef float f32x4u __attribute__((ext_vector_type(4), aligned(4)));  // 4B-aligned vec load

#define NN   512
#define UU   2048
#define VV   43
#define HH   512
#define KMIX 10
#define NCLS 512
#define EPSF 1e-5f
#define KCAT 555     // H + V

// d_out offsets (floats)
#define OFF_DIST  0
#define OFF_H2    262144
#define OFF_H3    524288
#define OFF_PHI   786432
#define OFF_WT    1835008
#define OFF_KAPPA 1857024

__device__ __forceinline__ ushortT f2bf(float f) {
    unsigned int u = __builtin_bit_cast(unsigned int, f);
    u = (u + 0x7fffu + ((u >> 16) & 1u)) >> 16;
    return (ushortT)u;
}

// ---------------------------------------------------------------------------
// Fused attention window. Changes vs R5:
//  * abk dots are wave-parallel (chain depth 9, coalesced 256B loads) instead
//    of 70-deep strided per-thread loops.
//  * chunk-0 cx row loads issued at kernel entry (depend only on n,t); their
//    HBM/L3 latency hides under abk+phi compute. nchunks >= 1 always.
__global__ __launch_bounds__(256, 2) void attn_kernel(
    const float* __restrict__ xt, const float* __restrict__ cx,
    const float* __restrict__ eh, const float* __restrict__ wt_1,
    const float* __restrict__ Ww, const float* __restrict__ Wb,
    const float* __restrict__ kappa_prev,
    float* __restrict__ phi_out, float* __restrict__ wt_out,
    float* __restrict__ kappa_out, ushortT* __restrict__ A2)
{
    __shared__ float x[KCAT];
    __shared__ float sm[32];
    __shared__ float aL[KMIX], bL[KMIX], kL[KMIX], um[KMIX];
    __shared__ float red[4*VV];
    __shared__ float wtv[VV+1];

    int n = blockIdx.x, t = threadIdx.x;
    int lane = t & 63, wid = t >> 6;
    const float* cxn = cx + (size_t)n*UU*VV;

    // ---- chunk-0 loads first: fly under abk+phi ----
    const float* rowp0 = cxn + (size_t)t*VV;
    f32x4u r0[10]; f32x4u rt0;
#pragma unroll
    for (int q = 0; q < 10; ++q) r0[q] = *(const f32x4u*)(rowp0 + q*4);
    rt0 = *(const f32x4u*)(rowp0 + 39);

    // ---- abk: stage x, then wave-parallel dots ----
    for (int i = t; i < KCAT; i += 256)
        x[i] = (i < HH) ? eh[(size_t)n*HH + i] : wt_1[n*VV + (i - HH)];
    __syncthreads();
#pragma unroll
    for (int rr = 0; rr < 8; ++rr) {
        int g = rr*4 + wid;
        float v = 0.f;
        if (g < 30) {
            const float* w = Ww + (size_t)g*KCAT;
#pragma unroll
            for (int q = 0; q < 9; ++q) {
                int i = q*64 + lane;
                if (i < KCAT) v += x[i]*w[i];
            }
        }
        v += __shfl_xor(v, 32, 64); v += __shfl_xor(v, 16, 64); v += __shfl_xor(v, 8, 64);
        v += __shfl_xor(v, 4, 64);  v += __shfl_xor(v, 2, 64);  v += __shfl_xor(v, 1, 64);
        if (lane == 0 && g < 30) sm[g] = v;
    }
    __syncthreads();
    if (t < 30) {
        float e = expf(sm[t] + Wb[t]);
        if (t < 10)       aL[t] = e + EPSF;
        else if (t < 20)  bL[t-10] = e + EPSF;
        else { float kap = kappa_prev[n*KMIX + (t-20)] + e; kL[t-20] = kap;
               kappa_out[n*KMIX + (t-20)] = kap; }
    }
    __syncthreads();
    // per-k numeric support end: kappa + sqrt(max(60 + ln(alpha), 0)/beta)
    if (t < KMIX)
        um[t] = kL[t] + sqrtf(fmaxf(60.f + logf(aL[t]), 0.f) / bL[t]);
    __syncthreads();
    float ulim = um[0];
#pragma unroll
    for (int k = 1; k < KMIX; ++k) ulim = fmaxf(ulim, um[k]);
    int nchunks = min(8, (int)(ulim) / 256 + 1);
    nchunks = __builtin_amdgcn_readfirstlane(nchunks);

    // ---- phi: exact for all u; thread t owns u = c*256+t ----
    float phi_reg[8];
#pragma unroll
    for (int c = 0; c < 8; ++c) {
        int u = c*256 + t; float uu = (float)u, s = 0.f;
#pragma unroll
        for (int k = 0; k < KMIX; ++k) { float d = kL[k] - uu; s += aL[k]*expf(-bL[k]*d*d); }
        phi_reg[c] = s;
        phi_out[(size_t)n*UU + u] = s;
    }

    // ---- wt: chunk 0 from prefetched regs ----
    float acc[VV];
    {
        float p = phi_reg[0];
#pragma unroll
        for (int q = 0; q < 10; ++q) {
            acc[q*4+0] = r0[q].x*p; acc[q*4+1] = r0[q].y*p;
            acc[q*4+2] = r0[q].z*p; acc[q*4+3] = r0[q].w*p;
        }
        acc[40] = rt0.y*p; acc[41] = rt0.z*p; acc[42] = rt0.w*p;
    }
    // rare extra chunks (live-support truncation)
#pragma unroll
    for (int c = 1; c < 8; ++c) {
        if (c < nchunks) {
            const float* rowp = cxn + (size_t)(c*256 + t)*VV;
            f32x4u r[10];
#pragma unroll
            for (int q = 0; q < 10; ++q) r[q] = *(const f32x4u*)(rowp + q*4);
            f32x4u rt = *(const f32x4u*)(rowp + 39);
            float p = phi_reg[c];
#pragma unroll
            for (int q = 0; q < 10; ++q) {
                acc[q*4+0] += r[q].x*p; acc[q*4+1] += r[q].y*p;
                acc[q*4+2] += r[q].z*p; acc[q*4+3] += r[q].w*p;
            }
            acc[40] += rt.y*p; acc[41] += rt.z*p; acc[42] += rt.w*p;
        }
    }

    // ---- reduce 256 threads -> wt[43] ----
#pragma unroll
    for (int v = 0; v < VV; ++v) {
        float val = acc[v];
#pragma unroll
        for (int off = 32; off > 0; off >>= 1) val += __shfl_down(val, off, 64);
        if (lane == 0) red[wid*VV + v] = val;
    }
    __syncthreads();
    if (t < VV) {
        float w4 = red[t] + red[VV+t] + red[2*VV+t] + red[3*VV+t];
        wt_out[n*VV + t] = w4; wtv[t] = w4;
    }
    __syncthreads();
    if (t < 64) {
        float v = (t == 0) ? xt[n] : (t < 44 ? wtv[t-1] : 0.f);
        A2[(size_t)n*64 + t] = f2bf(v);
    }
}

// ---------------------------------------------------------------------------
// One fused pack: bf16 weight copies + padded W2i + bf16 h2p/h3p rows
__global__ __launch_bounds__(256) void pack_all(
    const float* __restrict__ w2ih, const float* __restrict__ w2hh,
    const float* __restrict__ w3ih, const float* __restrict__ w3hh,
    const float* __restrict__ Yw, const float* __restrict__ h2p, const float* __restrict__ h3p,
    ushortT* __restrict__ W2i, ushortT* __restrict__ W2h,
    ushortT* __restrict__ W3i, ushortT* __restrict__ W3h,
    ushortT* __restrict__ Ywb, ushortT* __restrict__ A2h, ushortT* __restrict__ A3h)
{
    int idx = blockIdx.x*256 + threadIdx.x;
    if (idx < 98304) { int r = idx >> 6, c = idx & 63;
        W2i[idx] = f2bf(c < 44 ? w2ih[r*44 + c] : 0.f); return; }
    idx -= 98304;
    if (idx < 786432) { W2h[idx] = f2bf(w2hh[idx]); return; }
    idx -= 786432;
    if (idx < 786432) { W3i[idx] = f2bf(w3ih[idx]); return; }
    idx -= 786432;
    if (idx < 786432) { W3h[idx] = f2bf(w3hh[idx]); return; }
    idx -= 786432;
    if (idx < 262144) { Ywb[idx] = f2bf(Yw[idx]); return; }
    idx -= 262144;
    if (idx < 262144) { A2h[idx] = f2bf(h2p[idx]); return; }
    idx -= 262144;
    if (idx < 262144) { A3h[idx] = f2bf(h3p[idx]); return; }
}

// ---------------------------------------------------------------------------
// Fused gate-grouped MFMA GEMM + epilogue.
// Changes vs R5: LDS double-buffered (one barrier per K-step instead of two),
// register prefetch depth 2 (loads for s+2 issued at step s -> ~2 phases of
// latency cover; compiler emits counted vmcnt, no full drain mid-loop).
template<int NG, int NSA, int NSB, int EPI>
__global__ __launch_bounds__(256) void gemm_fused(
    const ushortT* __restrict__ Ai, const ushortT* __restrict__ Wi,
    const ushortT* __restrict__ Ah, const ushortT* __restrict__ Wh,
    const float* __restrict__ bih, const float* __restrict__ bhh,
    const float* __restrict__ hprev, const float* __restrict__ resv,
    float* __restrict__ outF, ushortT* __restrict__ outB, const float* __restrict__ Yb)
{
    constexpr int NS = NSA + NSB;
    __shared__ ushortT lds0[(NG+1)*32*64];
    __shared__ ushortT lds1[(NG+1)*32*64];

    int tid = threadIdx.x, lane = tid & 63, wid = tid >> 6;
    int wm = wid >> 1, wj = wid & 1;
    int bj0 = blockIdx.x*32, bm0 = blockIdx.y*32;
    int fcol = lane & 15, g2 = lane >> 4;

    float4 stgA[NG+1], stgB[NG+1];

    auto loadregs = [&](int s, float4 (&dst)[NG+1]) {
        const ushortT* Ab; const ushortT* Wb_; int K, kb;
        if (s < NSA) { Ab = Ai; Wb_ = Wi; K = NSA*64; kb = s*64; }
        else         { Ab = Ah; Wb_ = Wh; K = NSB*64; kb = (s - NSA)*64; }
        { int row = tid >> 3, slot = tid & 7;
          dst[0] = *(const float4*)(Ab + (size_t)(bm0 + row)*K + kb + slot*8); }
#pragma unroll
        for (int q = 1; q <= NG; ++q) {
            int local = (q-1)*256 + tid;
            int brow = local >> 3, slot = local & 7;
            int gate = brow >> 5, r = brow & 31;
            dst[q] = *(const float4*)(Wb_ + (size_t)(gate*512 + bj0 + r)*K + kb + slot*8);
        }
    };
    auto stow = [&](const float4 (&src)[NG+1], ushortT* buf) {
        { int row = tid >> 3, slot = tid & 7;
          *(float4*)(buf + row*64 + (slot ^ (row & 7))*8) = src[0]; }
#pragma unroll
        for (int q = 1; q <= NG; ++q) {
            int local = (q-1)*256 + tid;
            int brow = local >> 3, slot = local & 7;
            *(float4*)(buf + 2048 + brow*64 + (slot ^ (brow & 7))*8) = src[q];
        }
    };

    f32x4 aR = {0.f,0.f,0.f,0.f}, aZ = {0.f,0.f,0.f,0.f};
    f32x4 aN1 = {0.f,0.f,0.f,0.f}, aN2 = {0.f,0.f,0.f,0.f};

    int ra = wm*16 + fcol, rb = wj*16 + fcol;

    loadregs(0, stgA);
    stow(stgA, lds0);
    loadregs(1, stgB);
    __syncthreads();

#pragma unroll
    for (int s = 0; s < NS; ++s) {
        ushortT* cur = (s & 1) ? lds1 : lds0;
        ushortT* nxt = (s & 1) ? lds0 : lds1;
        if (s + 2 < NS) {
            if (s & 1) loadregs(s + 2, stgB); else loadregs(s + 2, stgA);
        }
        // fragment reads from current buffer (A at base, B at +2048)
        bf16x8 af0 = *(const bf16x8*)(cur + ra*64 + ((g2    ) ^ (ra & 7))*8);
        bf16x8 af1 = *(const bf16x8*)(cur + ra*64 + ((4 + g2) ^ (ra & 7))*8);
        bf16x8 b0[NG], b1[NG];
#pragma unroll
        for (int g = 0; g < NG; ++g) {
            int rbt = g*32 + rb;
            b0[g] = *(const bf16x8*)(cur + 2048 + rbt*64 + ((g2    ) ^ (rbt & 7))*8);
            b1[g] = *(const bf16x8*)(cur + 2048 + rbt*64 + ((4 + g2) ^ (rbt & 7))*8);
        }
        // stow next tile into the other buffer (its loads are 1-2 phases old)
        if (s + 1 < NS) {
            if (s & 1) stow(stgA, nxt); else stow(stgB, nxt);
        }
        // MFMAs
        aR = __builtin_amdgcn_mfma_f32_16x16x32_bf16(af0, b0[0], aR, 0, 0, 0);
        aR = __builtin_amdgcn_mfma_f32_16x16x32_bf16(af1, b1[0], aR, 0, 0, 0);
        if constexpr (NG >= 2) {
            aZ = __builtin_amdgcn_mfma_f32_16x16x32_bf16(af0, b0[1], aZ, 0, 0, 0);
            aZ = __builtin_amdgcn_mfma_f32_16x16x32_bf16(af1, b1[1], aZ, 0, 0, 0);
        }
        if constexpr (NG >= 3) {
            if (s < NSA) {
                aN1 = __builtin_amdgcn_mfma_f32_16x16x32_bf16(af0, b0[2], aN1, 0, 0, 0);
                aN1 = __builtin_amdgcn_mfma_f32_16x16x32_bf16(af1, b1[2], aN1, 0, 0, 0);
            } else {
                aN2 = __builtin_amdgcn_mfma_f32_16x16x32_bf16(af0, b0[2], aN2, 0, 0, 0);
                aN2 = __builtin_amdgcn_mfma_f32_16x16x32_bf16(af1, b1[2], aN2, 0, 0, 0);
            }
        }
        __syncthreads();
    }

    int row0 = bm0 + wm*16 + (lane >> 4)*4;
    int col  = bj0 + wj*16 + fcol;
    if constexpr (EPI == 0) {
        float b = Yb[col];
#pragma unroll
        for (int e = 0; e < 4; ++e)
            outF[(size_t)(row0 + e)*512 + col] = aR[e] + b;
    } else {
        float b_r  = bih[col] + bhh[col];
        float b_z  = bih[512 + col] + bhh[512 + col];
        float b_ni = bih[1024 + col];
        float b_nh = bhh[1024 + col];
#pragma unroll
        for (int e = 0; e < 4; ++e) {
            size_t off = (size_t)(row0 + e)*512 + col;
            float r  = 1.f/(1.f + expf(-(aR[e] + b_r)));
            float z  = 1.f/(1.f + expf(-(aZ[e] + b_z)));
            float nn = tanhf(aN1[e] + b_ni + r*(aN2[e] + b_nh));
            float h  = (1.f - z)*nn + z*hprev[off];
            outF[off] = h;
            float xo = (EPI == 2) ? (h + resv[off]) : h;
            outB[off] = f2bf(fmaxf(xo, 0.f));
        }
    }
}

// ---------------------------------------------------------------------------
extern "C" void kernel_launch(void* const* d_in, const int* in_sizes, int n_in,
                              void* d_out, int out_size, void* d_ws, size_t ws_size,
                              hipStream_t stream)
{
    const float* xt   = (const float*)d_in[0];
    const float* cx   = (const float*)d_in[1];
    const float* eh   = (const float*)d_in[2];
    const float* wt_1 = (const float*)d_in[3];
    const float* h2p  = (const float*)d_in[4];
    const float* h3p  = (const float*)d_in[5];
    const float* kp   = (const float*)d_in[6];
    const float* Ww   = (const float*)d_in[7];
    const float* Wb   = (const float*)d_in[8];
    const float* w2ih = (const float*)d_in[9];
    const float* w2hh = (const float*)d_in[10];
    const float* b2ih = (const float*)d_in[11];
    const float* b2hh = (const float*)d_in[12];
    const float* w3ih = (const float*)d_in[13];
    const float* w3hh = (const float*)d_in[14];
    const float* b3ih = (const float*)d_in[15];
    const float* b3hh = (const float*)d_in[16];
    const float* Yw   = (const float*)d_in[17];
    const float* Yb   = (const float*)d_in[18];

    float* out = (float*)d_out;
    float* dist = out + OFF_DIST;
    float* h2o  = out + OFF_H2;
    float* h3o  = out + OFF_H3;
    float* phi  = out + OFF_PHI;
    float* wto  = out + OFF_WT;
    float* kapo = out + OFF_KAPPA;

    char* p = (char*)d_ws;
    ushortT* W2i = (ushortT*)p;  p += (size_t)1536*64*2;
    ushortT* W2h = (ushortT*)p;  p += (size_t)1536*512*2;
    ushortT* W3i = (ushortT*)p;  p += (size_t)1536*512*2;
    ushortT* W3h = (ushortT*)p;  p += (size_t)1536*512*2;
    ushortT* Ywb = (ushortT*)p;  p += (size_t)512*512*2;
    ushortT* A2h = (ushortT*)p;  p += (size_t)512*512*2;
    ushortT* A3h = (ushortT*)p;  p += (size_t)512*512*2;
    ushortT* A2  = (ushortT*)p;  p += (size_t)512*64*2;
    ushortT* A3i = (ushortT*)p;  p += (size_t)512*512*2;
    ushortT* Ad  = (ushortT*)p;  p += (size_t)512*512*2;

    attn_kernel<<<NN, 256, 0, stream>>>(xt, cx, eh, wt_1, Ww, Wb, kp, phi, wto, kapo, A2);
    pack_all<<<12672, 256, 0, stream>>>(w2ih, w2hh, w3ih, w3hh, Yw, h2p, h3p,
                                        W2i, W2h, W3i, W3h, Ywb, A2h, A3h);
    // GRU2: gi from [xt|wt] @ w2ih^T (K=64 padded), gh from h2p @ w2hh^T (K=512)
    gemm_fused<3, 1, 8, 1><<<dim3(16, 16), 256, 0, stream>>>(
        A2, W2i, A2h, W2h, b2ih, b2hh, h2p, nullptr, h2o, A3i, nullptr);
    // GRU3: gi from relu(h2) @ w3ih^T, gh from h3p @ w3hh^T
    gemm_fused<3, 8, 8, 2><<<dim3(16, 16), 256, 0, stream>>>(
        A3i, W3i, A3h, W3h, b3ih, b3hh, h3p, h2o, h3o, Ad, nullptr);
    // dist = relu(h3+h2) @ Yw^T + Yb
    gemm_fused<1, 8, 0, 0><<<dim3(16, 16), 256, 0, stream>>>(
        Ad, Ywb, nullptr, nullptr, nullptr, nullptr, nullptr, nullptr, dist, nullptr, Yb);
}